// Round 1
// baseline (1188.395 us; speedup 1.0000x reference)
//
#include <hip/hip_runtime.h>
#include <hip/hip_bf16.h>

typedef __attribute__((ext_vector_type(8))) short short8;
typedef __attribute__((ext_vector_type(4))) float floatx4;

#define SEQ 2048
#define EMB 2048
#define NH 16
#define HD 128
#define E3 6144

static __device__ __forceinline__ unsigned short f2bf(float f) {
  unsigned u = __builtin_bit_cast(unsigned, f);
  u += 0x7fffu + ((u >> 16) & 1u);
  return (unsigned short)(u >> 16);
}

// ---- transpose+convert W: [2048][6144] f32 -> Wt [6144][2048] bf16 ----
__global__ void k_tw(const float* __restrict__ W, unsigned short* __restrict__ Wt) {
  __shared__ unsigned short t[32][33];
  int tx = threadIdx.x, ty = threadIdx.y;
  int e0 = blockIdx.x * 32, d0 = blockIdx.y * 32;
#pragma unroll
  for (int k = 0; k < 4; k++)
    t[ty + k * 8][tx] = f2bf(W[(long)(d0 + ty + k * 8) * E3 + e0 + tx]);
  __syncthreads();
#pragma unroll
  for (int k = 0; k < 4; k++)
    Wt[(long)(e0 + ty + k * 8) * EMB + d0 + tx] = t[tx][ty + k * 8];
}

// ---- transpose V-third of qkv -> Vt [32][128][2048] bf16 ----
__global__ void k_tv(const unsigned short* __restrict__ qkv, unsigned short* __restrict__ Vt) {
  __shared__ unsigned short t[32][33];
  int tx = threadIdx.x, ty = threadIdx.y;
  int z = blockIdx.z;              // b*16 + h
  int b = z >> 4, h = z & 15;
  int s0 = blockIdx.x * 32, d0 = blockIdx.y * 32;
#pragma unroll
  for (int k = 0; k < 4; k++) {
    int s = s0 + ty + k * 8;
    t[ty + k * 8][tx] = qkv[(long)(b * SEQ + s) * E3 + 2 * EMB + h * HD + d0 + tx];
  }
  __syncthreads();
#pragma unroll
  for (int k = 0; k < 4; k++) {
    int d = d0 + ty + k * 8;
    Vt[((long)z * HD + d) * SEQ + s0 + tx] = t[tx][ty + k * 8];
  }
}

// ---- generic 128x128-tile bf16 MFMA GEMM: C[m][n] = sum_k A[m][k]*Bt[n][k] ----
// MODE 0: A = X (f32, convert on stage), Bt = Wt, C = qkv bf16 (+bias). M=4096 N=6144 K=2048
// MODE 1: A = Q rows of qkv (bf16), Bt = K rows of qkv, C = logits f32 * scale. per z=bh.
// MODE 2: A = scores (f32, convert on stage), Bt = Vt, C = attention f32 strided. per z=bh.
template <int MODE>
__global__ __launch_bounds__(256, 2) void k_gemm(const void* __restrict__ Abase,
                                                 const unsigned short* __restrict__ Btb,
                                                 void* __restrict__ Cb,
                                                 const float* __restrict__ bias,
                                                 float scale) {
  constexpr int K = (MODE == 1) ? 128 : 2048;
  constexpr long sA = (MODE == 0) ? EMB : (MODE == 1) ? E3 : SEQ;
  constexpr long sB = (MODE == 0) ? EMB : (MODE == 1) ? E3 : SEQ;
  constexpr long sC = (MODE == 0) ? E3 : (MODE == 1) ? SEQ : EMB;
  constexpr bool AF32 = (MODE != 1);

  int z = blockIdx.z;
  long offA = 0, offB = 0, offC = 0;
  if (MODE == 1) {
    int b = z >> 4, h = z & 15;
    offA = (long)(b * SEQ) * E3 + h * HD;          // Q third
    offB = (long)(b * SEQ) * E3 + EMB + h * HD;    // K third
    offC = (long)z * SEQ * SEQ;
  } else if (MODE == 2) {
    int b = z >> 4, h = z & 15;
    offA = (long)z * SEQ * SEQ;                    // scores for this head
    offB = (long)z * HD * SEQ;                     // Vt for this head
    offC = (long)b * SEQ * EMB + h * HD;           // attention, [B,S,H*hd]
  }

  __shared__ unsigned short As[128][72];  // +8 pad: 144B rows, 16B-aligned, 2-way banks
  __shared__ unsigned short Bs[128][72];

  int tid = threadIdx.x;
  int lane = tid & 63;
  int wave = tid >> 6;
  int wm = wave >> 1, wn = wave & 1;
  int quad = lane >> 4, l16 = lane & 15;
  long tM = (long)blockIdx.y * 128;
  long tN = (long)blockIdx.x * 128;

  const float* Af = (const float*)Abase;
  const unsigned short* Ab = (const unsigned short*)Abase;

  floatx4 acc[4][4] = {};

  for (int k0 = 0; k0 < K; k0 += 64) {
#pragma unroll
    for (int c = 0; c < 4; c++) {
      int id = tid + 256 * c;      // 0..1023
      int r = id >> 3;             // 0..127
      int col = (id & 7) * 8;      // 0..56
      if (AF32) {
        const float* s = Af + offA + (tM + r) * sA + k0 + col;
        float4 f0 = *(const float4*)s;
        float4 f1 = *(const float4*)(s + 4);
        uint4 u;
        u.x = (unsigned)f2bf(f0.x) | ((unsigned)f2bf(f0.y) << 16);
        u.y = (unsigned)f2bf(f0.z) | ((unsigned)f2bf(f0.w) << 16);
        u.z = (unsigned)f2bf(f1.x) | ((unsigned)f2bf(f1.y) << 16);
        u.w = (unsigned)f2bf(f1.z) | ((unsigned)f2bf(f1.w) << 16);
        *(uint4*)&As[r][col] = u;
      } else {
        *(uint4*)&As[r][col] = *(const uint4*)(Ab + offA + (tM + r) * sA + k0 + col);
      }
      *(uint4*)&Bs[r][col] = *(const uint4*)(Btb + offB + (tN + r) * sB + k0 + col);
    }
    __syncthreads();
#pragma unroll
    for (int ks = 0; ks < 2; ks++) {
      short8 af[4], bfr[4];
#pragma unroll
      for (int i = 0; i < 4; i++)
        af[i] = *(const short8*)&As[wm * 64 + i * 16 + l16][ks * 32 + quad * 8];
#pragma unroll
      for (int j = 0; j < 4; j++)
        bfr[j] = *(const short8*)&Bs[wn * 64 + j * 16 + l16][ks * 32 + quad * 8];
#pragma unroll
      for (int i = 0; i < 4; i++)
#pragma unroll
        for (int j = 0; j < 4; j++)
          acc[i][j] = __builtin_amdgcn_mfma_f32_16x16x32_bf16(af[i], bfr[j], acc[i][j], 0, 0, 0);
    }
    __syncthreads();
  }

  // epilogue: C/D layout col=lane&15, row=quad*4+reg (verified m89/m91)
#pragma unroll
  for (int i = 0; i < 4; i++)
#pragma unroll
    for (int j = 0; j < 4; j++)
#pragma unroll
      for (int r = 0; r < 4; r++) {
        long row = tM + wm * 64 + i * 16 + quad * 4 + r;
        long col = tN + wn * 64 + j * 16 + l16;
        float v = acc[i][j][r];
        if (MODE == 0) {
          ((unsigned short*)Cb)[row * sC + col] = f2bf(v + bias[col]);
        } else if (MODE == 1) {
          ((float*)Cb)[offC + row * sC + col] = v * scale;
        } else {
          ((float*)Cb)[offC + row * sC + col] = v;
        }
      }
}

// ---- row softmax in place: 65536 rows x 2048 ----
__global__ __launch_bounds__(256) void k_softmax(float* __restrict__ sc) {
  long row = blockIdx.x;
  float* p = sc + row * 2048;
  int t = threadIdx.x;
  int lane = t & 63, wave = t >> 6;
  float4 v0 = *(float4*)(p + t * 8);
  float4 v1 = *(float4*)(p + t * 8 + 4);
  float m = fmaxf(fmaxf(fmaxf(v0.x, v0.y), fmaxf(v0.z, v0.w)),
                  fmaxf(fmaxf(v1.x, v1.y), fmaxf(v1.z, v1.w)));
#pragma unroll
  for (int o = 32; o > 0; o >>= 1) m = fmaxf(m, __shfl_xor(m, o, 64));
  __shared__ float rm[4], rs[4];
  if (lane == 0) rm[wave] = m;
  __syncthreads();
  m = fmaxf(fmaxf(rm[0], rm[1]), fmaxf(rm[2], rm[3]));
  v0.x = __expf(v0.x - m); v0.y = __expf(v0.y - m);
  v0.z = __expf(v0.z - m); v0.w = __expf(v0.w - m);
  v1.x = __expf(v1.x - m); v1.y = __expf(v1.y - m);
  v1.z = __expf(v1.z - m); v1.w = __expf(v1.w - m);
  float s = v0.x + v0.y + v0.z + v0.w + v1.x + v1.y + v1.z + v1.w;
#pragma unroll
  for (int o = 32; o > 0; o >>= 1) s += __shfl_xor(s, o, 64);
  if (lane == 0) rs[wave] = s;
  __syncthreads();
  s = rs[0] + rs[1] + rs[2] + rs[3];
  float inv = 1.0f / s;
  v0.x *= inv; v0.y *= inv; v0.z *= inv; v0.w *= inv;
  v1.x *= inv; v1.y *= inv; v1.z *= inv; v1.w *= inv;
  *(float4*)(p + t * 8) = v0;
  *(float4*)(p + t * 8 + 4) = v1;
}

extern "C" void kernel_launch(void* const* d_in, const int* in_sizes, int n_in,
                              void* d_out, int out_size, void* d_ws, size_t ws_size,
                              hipStream_t stream) {
  const float* X = (const float*)d_in[0];      // [2,2048,2048]
  const float* W = (const float*)d_in[1];      // [2048,6144]
  const float* bias = (const float*)d_in[2];   // [6144]
  float* out = (float*)d_out;
  float* attn = out;                           // [2,2048,2048]
  float* scores = out + (long)2 * SEQ * EMB;   // [2,16,2048,2048]

  // workspace: Wt (25.2MB) | qkv bf16 (50.3MB) | Vt (16.8MB)  => ~92.3 MB
  unsigned short* Wt = (unsigned short*)d_ws;
  unsigned short* qkv = Wt + (long)E3 * EMB;
  unsigned short* Vt = qkv + (long)2 * SEQ * E3;

  k_tw<<<dim3(E3 / 32, EMB / 32), dim3(32, 8), 0, stream>>>(W, Wt);
  k_gemm<0><<<dim3(E3 / 128, (2 * SEQ) / 128, 1), 256, 0, stream>>>(X, Wt, qkv, bias, 1.0f);
  k_tv<<<dim3(SEQ / 32, HD / 32, 2 * NH), dim3(32, 8), 0, stream>>>(qkv, Vt);
  k_gemm<1><<<dim3(SEQ / 128, SEQ / 128, 2 * NH), 256, 0, stream>>>(qkv, qkv, scores, nullptr,
                                                                    0.08838834764831843f);
  k_softmax<<<dim3(2 * NH * SEQ), 256, 0, stream>>>(scores);
  k_gemm<2><<<dim3(1, SEQ / 128, 2 * NH), 256, 0, stream>>>(scores, Vt, attn, nullptr, 1.0f);
}